// Round 1
// baseline (2128.688 us; speedup 1.0000x reference)
//
#include <hip/hip_runtime.h>
#include <math.h>

// Problem constants
#define B_ 4
#define S_ 1024
#define D_ 1024
#define H_ 16
#define DK_ 64

// ---------------------------------------------------------------------------
// GEMM: Y[M,N] = X[M,K] @ W[N,K]^T + bvec[N]
// Both X and W row-major with contiguous K (torch Linear layout).
// BM=BN=64, BK=16, 256 threads, 4x4 microtile per thread. Pure f32 baseline.
// ---------------------------------------------------------------------------
__global__ __launch_bounds__(256) void gemm_bt(
    const float* __restrict__ X, const float* __restrict__ W,
    const float* __restrict__ bvec, float* __restrict__ Y,
    int M, int N, int K)
{
    __shared__ float Xs[64][17];  // +1 pad: Ws reads stride 68 => 2-way (free)
    __shared__ float Ws[64][17];

    const int t  = threadIdx.x;
    const int tx = t & 15;        // 0..15 -> n micro
    const int ty = t >> 4;        // 0..15 -> m micro
    const int m0 = blockIdx.y * 64;
    const int n0 = blockIdx.x * 64;

    const int lrow = t >> 2;        // 0..63
    const int lc4  = (t & 3) * 4;   // 0,4,8,12

    float acc[4][4] = {};

    for (int kt = 0; kt < K; kt += 16) {
        float4 xv = *(const float4*)(X + (size_t)(m0 + lrow) * K + kt + lc4);
        float4 wv = *(const float4*)(W + (size_t)(n0 + lrow) * K + kt + lc4);
        Xs[lrow][lc4 + 0] = xv.x; Xs[lrow][lc4 + 1] = xv.y;
        Xs[lrow][lc4 + 2] = xv.z; Xs[lrow][lc4 + 3] = xv.w;
        Ws[lrow][lc4 + 0] = wv.x; Ws[lrow][lc4 + 1] = wv.y;
        Ws[lrow][lc4 + 2] = wv.z; Ws[lrow][lc4 + 3] = wv.w;
        __syncthreads();
        #pragma unroll
        for (int kk = 0; kk < 16; ++kk) {
            float a0 = Xs[ty * 4 + 0][kk];
            float a1 = Xs[ty * 4 + 1][kk];
            float a2 = Xs[ty * 4 + 2][kk];
            float a3 = Xs[ty * 4 + 3][kk];
            float w0 = Ws[tx * 4 + 0][kk];
            float w1 = Ws[tx * 4 + 1][kk];
            float w2 = Ws[tx * 4 + 2][kk];
            float w3 = Ws[tx * 4 + 3][kk];
            acc[0][0] += a0 * w0; acc[0][1] += a0 * w1; acc[0][2] += a0 * w2; acc[0][3] += a0 * w3;
            acc[1][0] += a1 * w0; acc[1][1] += a1 * w1; acc[1][2] += a1 * w2; acc[1][3] += a1 * w3;
            acc[2][0] += a2 * w0; acc[2][1] += a2 * w1; acc[2][2] += a2 * w2; acc[2][3] += a2 * w3;
            acc[3][0] += a3 * w0; acc[3][1] += a3 * w1; acc[3][2] += a3 * w2; acc[3][3] += a3 * w3;
        }
        __syncthreads();
    }

    #pragma unroll
    for (int i = 0; i < 4; ++i) {
        int m = m0 + ty * 4 + i;
        #pragma unroll
        for (int j = 0; j < 4; ++j) {
            int n = n0 + tx * 4 + j;
            Y[(size_t)m * N + n] = acc[i][j] + bvec[n];
        }
    }
}

// ---------------------------------------------------------------------------
// Flash-style attention, f32 baseline.
// One block = (b, h, 16 q rows). 256 threads. K/V tiles of 64 rows in LDS.
// Online softmax state (m,l,alpha) in LDS, updated by 16 row-leader threads.
// Block swizzle: all 16 heads of a (b,qt) group get bids congruent mod 8 so
// (assuming XCD = bid % 8 round robin) the stride-16 bias lines are shared
// within one XCD's L2.
// ---------------------------------------------------------------------------
__global__ __launch_bounds__(256) void attn_kernel(
    const float* __restrict__ Q, const float* __restrict__ K,
    const float* __restrict__ V, const float* __restrict__ bias,
    const int* __restrict__ mask, float* __restrict__ Xout)
{
    __shared__ float Qs[16][64];
    __shared__ float Ks[64][65];   // +1 pad: score reads lane=k stride 65 (free)
    __shared__ float Vt[64][64];   // PV reads lane=dk stride 1 (free)
    __shared__ float Sc[16][65];   // +1 pad: row-leader scan lanes hit distinct banks
    __shared__ float mrow[16], lrow[16], arow[16];

    const int t = threadIdx.x;
    // de-swizzle block id: bid = (g&7) + 8*(h + 16*(g>>3)),  g = b*64 + qt
    const int bid = blockIdx.x;
    const int r8  = bid & 7;
    const int v_  = bid >> 3;
    const int h   = v_ & 15;
    const int g   = ((v_ >> 4) << 3) + r8;
    const int qt  = g & 63;
    const int b   = g >> 6;
    const int q0  = qt * 16;

    const int dk = t & 63;   // 0..63 lane dim
    const int qi = t >> 6;   // 0..3 wave id -> rows qi*4..qi*4+3

    // load Q tile (16x64) with float4
    {
        int r  = t >> 4;          // 0..15
        int d4 = (t & 15) * 4;    // 0..60
        const float* src = Q + ((size_t)b * S_ + q0 + r) * D_ + h * 64 + d4;
        float4 v = *(const float4*)src;
        Qs[r][d4 + 0] = v.x; Qs[r][d4 + 1] = v.y;
        Qs[r][d4 + 2] = v.z; Qs[r][d4 + 3] = v.w;
    }
    if (t < 16) { mrow[t] = -INFINITY; lrow[t] = 0.0f; arow[t] = 0.0f; }

    bool mq[4];
    #pragma unroll
    for (int j = 0; j < 4; ++j)
        mq[j] = mask[b * S_ + q0 + qi * 4 + j] != 0;

    float acc[4] = {0.f, 0.f, 0.f, 0.f};

    for (int k0 = 0; k0 < S_; k0 += 64) {
        // stage K/V tiles: 4096 floats each, 16 per thread, coalesced
        #pragma unroll
        for (int it = 0; it < 16; ++it) {
            int f = t + 256 * it;
            int i = f >> 6, d = f & 63;
            size_t ga = ((size_t)b * S_ + k0 + i) * D_ + h * 64 + d;
            Ks[i][d] = K[ga];
            Vt[i][d] = V[ga];
        }
        __syncthreads();

        // scores: thread computes 4 rows x 1 col (col = dk)
        {
            const int kk = dk;
            bool mk = mask[b * S_ + k0 + kk] != 0;
            float s0 = 0.f, s1 = 0.f, s2 = 0.f, s3 = 0.f;
            #pragma unroll 16
            for (int d = 0; d < 64; ++d) {
                float kv = Ks[kk][d];
                s0 += Qs[qi * 4 + 0][d] * kv;
                s1 += Qs[qi * 4 + 1][d] * kv;
                s2 += Qs[qi * 4 + 2][d] * kv;
                s3 += Qs[qi * 4 + 3][d] * kv;
            }
            float sj[4] = {s0, s1, s2, s3};
            #pragma unroll
            for (int j = 0; j < 4; ++j) {
                int r = qi * 4 + j;
                float bv = bias[(((size_t)b * S_ + q0 + r) * S_ + k0 + kk) * H_ + h];
                float sc = (mq[j] && mk) ? (sj[j] + bv) * 0.125f : -1e9f;
                Sc[r][kk] = sc;
            }
        }
        __syncthreads();

        // online softmax: 16 row leaders
        if (t < 16) {
            float om = mrow[t];
            float rm = om;
            for (int k = 0; k < 64; ++k) rm = fmaxf(rm, Sc[t][k]);
            float a = __expf(om - rm);          // exp(-inf)=0 first tile
            float sum = 0.f;
            for (int k = 0; k < 64; ++k) {
                float p = __expf(Sc[t][k] - rm);
                Sc[t][k] = p;
                sum += p;
            }
            mrow[t] = rm;
            lrow[t] = lrow[t] * a + sum;
            arow[t] = a;
        }
        __syncthreads();

        // PV: thread accumulates 4 rows at col dk
        {
            float pv0 = 0.f, pv1 = 0.f, pv2 = 0.f, pv3 = 0.f;
            #pragma unroll 16
            for (int k = 0; k < 64; ++k) {
                float vv = Vt[k][dk];
                pv0 += Sc[qi * 4 + 0][k] * vv;
                pv1 += Sc[qi * 4 + 1][k] * vv;
                pv2 += Sc[qi * 4 + 2][k] * vv;
                pv3 += Sc[qi * 4 + 3][k] * vv;
            }
            acc[0] = acc[0] * arow[qi * 4 + 0] + pv0;
            acc[1] = acc[1] * arow[qi * 4 + 1] + pv1;
            acc[2] = acc[2] * arow[qi * 4 + 2] + pv2;
            acc[3] = acc[3] * arow[qi * 4 + 3] + pv3;
        }
        __syncthreads();
    }

    #pragma unroll
    for (int j = 0; j < 4; ++j) {
        int r = qi * 4 + j;
        Xout[((size_t)b * S_ + q0 + r) * D_ + h * 64 + dk] = acc[j] / lrow[r];
    }
}

// ---------------------------------------------------------------------------
extern "C" void kernel_launch(void* const* d_in, const int* in_sizes, int n_in,
                              void* d_out, int out_size, void* d_ws, size_t ws_size,
                              hipStream_t stream)
{
    const float* query = (const float*)d_in[0];
    const float* key   = (const float*)d_in[1];
    const float* value = (const float*)d_in[2];
    const float* abias = (const float*)d_in[3];
    const int*   mask  = (const int*)d_in[4];
    const float* Wq = (const float*)d_in[5];
    const float* bq = (const float*)d_in[6];
    const float* Wk = (const float*)d_in[7];
    const float* bk = (const float*)d_in[8];
    const float* Wv = (const float*)d_in[9];
    const float* bv = (const float*)d_in[10];
    const float* Wo = (const float*)d_in[11];
    const float* bo = (const float*)d_in[12];
    float* out = (float*)d_out;

    float* ws = (float*)d_ws;
    const size_t TSZ = (size_t)B_ * S_ * D_;  // 4 Mi elements
    float* Qp = ws;
    float* Kp = ws + TSZ;
    float* Vp = ws + 2 * TSZ;
    float* Xp = ws + 3 * TSZ;

    const int M = B_ * S_;  // 4096
    dim3 gproj(D_ / 64, M / 64);  // (16, 64)

    gemm_bt<<<gproj, 256, 0, stream>>>(query, Wq, bq, Qp, M, D_, D_);
    gemm_bt<<<gproj, 256, 0, stream>>>(key,   Wk, bk, Kp, M, D_, D_);
    gemm_bt<<<gproj, 256, 0, stream>>>(value, Wv, bv, Vp, M, D_, D_);

    attn_kernel<<<dim3(B_ * H_ * (S_ / 16)), 256, 0, stream>>>(Qp, Kp, Vp, abias, mask, Xp);

    gemm_bt<<<gproj, 256, 0, stream>>>(Xp, Wo, bo, out, M, D_, D_);
}

// Round 2
// 637.469 us; speedup vs baseline: 3.3393x; 3.3393x over previous
//
#include <hip/hip_runtime.h>
#include <hip/hip_bf16.h>
#include <math.h>

#define B_ 4
#define S_ 1024
#define D_ 1024
#define H_ 16
#define DK_ 64

typedef short bf16x8 __attribute__((ext_vector_type(8)));
typedef float f32x4 __attribute__((ext_vector_type(4)));

#define MFMA(a, b, c) __builtin_amdgcn_mfma_f32_16x16x32_bf16(a, b, c, 0, 0, 0)

// async global->LDS, 16B per lane. LDS dest = wave-uniform base + lane*16.
#define GLDS(gp, lp)                                                        \
    __builtin_amdgcn_global_load_lds(                                       \
        (const __attribute__((address_space(1))) void*)(const void*)(gp),   \
        (__attribute__((address_space(3))) void*)(void*)(lp), 16, 0, 0)

static __device__ __forceinline__ unsigned short f2bf(float f) {
    __hip_bfloat16 h = __float2bfloat16(f);
    return *reinterpret_cast<unsigned short*>(&h);
}

// ---------------------------------------------------------------------------
// f32 -> bf16 convert, float4 per thread
// ---------------------------------------------------------------------------
__global__ __launch_bounds__(256) void cvt_bf16(
    const float* __restrict__ in, unsigned short* __restrict__ out, int n4)
{
    int i = blockIdx.x * 256 + threadIdx.x;
    if (i >= n4) return;
    float4 v = ((const float4*)in)[i];
    ushort4 o;
    o.x = f2bf(v.x); o.y = f2bf(v.y); o.z = f2bf(v.z); o.w = f2bf(v.w);
    ((ushort4*)out)[i] = o;
}

// ---------------------------------------------------------------------------
// bf16 MFMA GEMM:  C[M=4096, N=1024] = X[4096,1024] @ W[1024,1024]^T + bvec
// X, W row-major, K contiguous. Tile BM=128, BN=64, BK=32. 256 thr / 4 waves,
// wave = 64x32 subtile = 4x2 grid of 16x16x32 MFMA. global_load_lds staging.
// mode 0: bf16 out row-major [M][1024]
// mode 1: bf16 out transposed per head -> [B][H][DK][S]  (for V)
// mode 2: f32 out row-major (final output)
// ---------------------------------------------------------------------------
__global__ __launch_bounds__(256, 2) void gemm_mfma(
    const unsigned short* __restrict__ X, const unsigned short* __restrict__ W,
    const float* __restrict__ bvec, void* __restrict__ Yv, int mode)
{
    __shared__ unsigned short As[128 * 32];  // [row][k], row = 64B (bank-balanced)
    __shared__ unsigned short Bs[64 * 32];

    const int t = threadIdx.x;
    const int w = t >> 6, l = t & 63;
    const int lane16 = l & 15, quad = l >> 4;
    const int m0 = blockIdx.y * 128, n0 = blockIdx.x * 64;
    const int wr = w >> 1, wc = w & 1;  // wave subtile origin (wr*64, wc*32)

    // staging addresses: A round i covers rows i*64 + w*16 + (l>>2), granule l&3
    const int arow = w * 16 + (l >> 2);
    const unsigned short* agp = X + (size_t)(m0 + arow) * 1024 + (l & 3) * 8;
    unsigned short* alp = As + w * 512 + l * 8;   // row*32 + (l&3)*8 == l*8 + w*512
    const unsigned short* bgp = W + (size_t)(n0 + arow) * 1024 + (l & 3) * 8;
    unsigned short* blp = Bs + w * 512 + l * 8;

    f32x4 zero = {0.f, 0.f, 0.f, 0.f};
    f32x4 acc[4][2];
    #pragma unroll
    for (int i = 0; i < 4; ++i)
        #pragma unroll
        for (int j = 0; j < 2; ++j) acc[i][j] = zero;

    for (int kt = 0; kt < 1024; kt += 32) {
        GLDS(agp + kt, alp);
        GLDS(agp + kt + 64 * 1024, alp + 64 * 32);
        GLDS(bgp + kt, blp);
        __syncthreads();

        bf16x8 af[4], bf[2];
        #pragma unroll
        for (int i = 0; i < 4; ++i)
            af[i] = *(const bf16x8*)(As + (wr * 64 + i * 16 + lane16) * 32 + quad * 8);
        #pragma unroll
        for (int j = 0; j < 2; ++j)
            bf[j] = *(const bf16x8*)(Bs + (wc * 32 + j * 16 + lane16) * 32 + quad * 8);

        #pragma unroll
        for (int i = 0; i < 4; ++i)
            #pragma unroll
            for (int j = 0; j < 2; ++j)
                acc[i][j] = MFMA(af[i], bf[j], acc[i][j]);
        __syncthreads();
    }

    // epilogue. C layout: col = lane16, row = quad*4 + reg
    float bv[2];
    #pragma unroll
    for (int j = 0; j < 2; ++j) bv[j] = bvec[n0 + wc * 32 + j * 16 + lane16];

    #pragma unroll
    for (int i = 0; i < 4; ++i) {
        #pragma unroll
        for (int j = 0; j < 2; ++j) {
            int n = n0 + wc * 32 + j * 16 + lane16;
            #pragma unroll
            for (int r = 0; r < 4; ++r) {
                size_t m = m0 + wr * 64 + i * 16 + quad * 4 + r;
                float val = acc[i][j][r] + bv[j];
                if (mode == 0) {
                    ((unsigned short*)Yv)[m * 1024 + n] = f2bf(val);
                } else if (mode == 1) {
                    int b = (int)(m >> 10), s = (int)(m & 1023);
                    int h = n >> 6, dk = n & 63;
                    ((unsigned short*)Yv)[(((size_t)(b * 16 + h) * 64 + dk) << 10) + s] = f2bf(val);
                } else {
                    ((float*)Yv)[m * 1024 + n] = val;
                }
            }
        }
    }
}

// ---------------------------------------------------------------------------
// MFMA flash attention. Block = (b, h, 64 q rows), 4 waves x 16 q rows.
// K tile [64 key][64 dk] bf16 LDS (xor-swizzled granules, 128B rows),
// V^T tile [64 dk][64 key] likewise. P round-trips LDS (C-layout -> A-layout).
// ---------------------------------------------------------------------------
__global__ __launch_bounds__(256, 2) void attn_mfma(
    const unsigned short* __restrict__ Qp, const unsigned short* __restrict__ Kp,
    const unsigned short* __restrict__ VpT, const float* __restrict__ bias,
    const int* __restrict__ mask, unsigned short* __restrict__ Xp)
{
    __shared__ unsigned short Ks[64 * 64];
    __shared__ unsigned short Vs[64 * 64];
    __shared__ unsigned short Ps[4][16 * 72];  // per-wave P, row stride 72 (bank pad)

    const int t = threadIdx.x;
    const int w = t >> 6, l = t & 63;
    const int lane16 = l & 15, quad = l >> 4;

    // de-swizzle: bid = (g&7) + 8*(h + 16*(g>>3)), g = b*16 + qt  (g in [0,64))
    const int bid = blockIdx.x;
    const int r8 = bid & 7, v_ = bid >> 3;
    const int h = v_ & 15;
    const int g = ((v_ >> 4) << 3) + r8;
    const int qt = g & 15, b = g >> 4;
    const int q0 = qt * 64;
    const int qrow0 = q0 + w * 16;  // this wave's 16 q rows

    // Q fragments held in registers for the whole K loop
    bf16x8 qf[2];
    #pragma unroll
    for (int c = 0; c < 2; ++c)
        qf[c] = *(const bf16x8*)(Qp + (size_t)(b * 1024 + qrow0 + lane16) * 1024
                                 + h * 64 + c * 32 + quad * 8);

    int mrow[4];
    size_t brow[4];  // bias row bases
    #pragma unroll
    for (int r = 0; r < 4; ++r) {
        int qg = qrow0 + quad * 4 + r;
        mrow[r] = mask[b * 1024 + qg];
        brow[r] = ((size_t)(b * 1024 + qg) * 1024) * 16 + h;
    }

    // staging: row = i0*32 + w*8 + (l>>3); lds granule l&7 holds global granule
    // (l&7) ^ (row&7); row&7 == (l>>3)&7 here.
    const int krow = w * 8 + (l >> 3);
    const int kgran = (l & 7) ^ ((l >> 3) & 7);
    const unsigned short* kg = Kp + ((size_t)(b * 1024 + krow) * 16 + h) * 64 + kgran * 8;
    unsigned short* klp = Ks + w * 512 + l * 8;
    const unsigned short* vg = VpT + ((size_t)(b * 16 + h) * 64 + krow) * 1024 + kgran * 8;
    unsigned short* vlp = Vs + w * 512 + l * 8;

    f32x4 zero = {0.f, 0.f, 0.f, 0.f};
    f32x4 o[4];
    #pragma unroll
    for (int j = 0; j < 4; ++j) o[j] = zero;
    float m_i[4] = {-1e30f, -1e30f, -1e30f, -1e30f};
    float l_i[4] = {0.f, 0.f, 0.f, 0.f};

    for (int k0 = 0; k0 < 1024; k0 += 64) {
        GLDS(kg + (size_t)k0 * 1024, klp);
        GLDS(kg + (size_t)(k0 + 32) * 1024, klp + 32 * 64);
        GLDS(vg + k0, vlp);
        GLDS(vg + k0 + 32 * 1024, vlp + 32 * 64);
        __syncthreads();

        // prefetch bias + key mask (independent of MFMA results)
        float bvv[4][4];
        int mk[4];
        #pragma unroll
        for (int j = 0; j < 4; ++j) {
            int keyg = k0 + j * 16 + lane16;
            mk[j] = mask[b * 1024 + keyg];
            #pragma unroll
            for (int r = 0; r < 4; ++r)
                bvv[j][r] = bias[brow[r] + (size_t)keyg * 16];
        }

        // S = Q @ K^T  (4 key tiles x 2 k-chunks)
        f32x4 s[4];
        #pragma unroll
        for (int j = 0; j < 4; ++j) {
            s[j] = zero;
            #pragma unroll
            for (int c = 0; c < 2; ++c) {
                bf16x8 kf = *(const bf16x8*)(Ks + (j * 16 + lane16) * 64
                                             + (((c * 4 + quad) ^ (lane16 & 7)) * 8));
                s[j] = MFMA(qf[c], kf, s[j]);
            }
        }

        // bias + scale + mask
        float sc[4][4];
        #pragma unroll
        for (int j = 0; j < 4; ++j)
            #pragma unroll
            for (int r = 0; r < 4; ++r)
                sc[j][r] = (mrow[r] && mk[j]) ? (s[j][r] + bvv[j][r]) * 0.125f : -1e9f;

        // online softmax per row (rows live in one quad's 16 lanes)
        float p[4][4];
        #pragma unroll
        for (int r = 0; r < 4; ++r) {
            float mx = fmaxf(fmaxf(sc[0][r], sc[1][r]), fmaxf(sc[2][r], sc[3][r]));
            #pragma unroll
            for (int d = 1; d < 16; d <<= 1) mx = fmaxf(mx, __shfl_xor(mx, d, 64));
            float mnew = fmaxf(m_i[r], mx);
            float alpha = __expf(m_i[r] - mnew);
            m_i[r] = mnew;
            float sum = 0.f;
            #pragma unroll
            for (int j = 0; j < 4; ++j) {
                p[j][r] = __expf(sc[j][r] - mnew);
                sum += p[j][r];
            }
            #pragma unroll
            for (int d = 1; d < 16; d <<= 1) sum += __shfl_xor(sum, d, 64);
            l_i[r] = l_i[r] * alpha + sum;
            #pragma unroll
            for (int jd = 0; jd < 4; ++jd) o[jd][r] *= alpha;
        }

        // P: C-layout -> LDS -> A-layout (same wave; compiler inserts lgkm waits)
        #pragma unroll
        for (int j = 0; j < 4; ++j)
            #pragma unroll
            for (int r = 0; r < 4; ++r)
                Ps[w][(quad * 4 + r) * 72 + j * 16 + lane16] = f2bf(p[j][r]);
        asm volatile("" ::: "memory");

        bf16x8 pf[2];
        #pragma unroll
        for (int c = 0; c < 2; ++c)
            pf[c] = *(const bf16x8*)(&Ps[w][lane16 * 72 + c * 32 + quad * 8]);

        // O += P @ V  (4 dk tiles x 2 key chunks)
        #pragma unroll
        for (int jd = 0; jd < 4; ++jd)
            #pragma unroll
            for (int c = 0; c < 2; ++c) {
                bf16x8 vf = *(const bf16x8*)(Vs + (jd * 16 + lane16) * 64
                                             + (((c * 4 + quad) ^ (lane16 & 7)) * 8));
                o[jd] = MFMA(pf[c], vf, o[jd]);
            }
        __syncthreads();
    }

    float inv[4];
    #pragma unroll
    for (int r = 0; r < 4; ++r) inv[r] = 1.0f / l_i[r];

    #pragma unroll
    for (int jd = 0; jd < 4; ++jd)
        #pragma unroll
        for (int r = 0; r < 4; ++r)
            Xp[(size_t)(b * 1024 + qrow0 + quad * 4 + r) * 1024
               + h * 64 + jd * 16 + lane16] = f2bf(o[jd][r] * inv[r]);
}

// ---------------------------------------------------------------------------
extern "C" void kernel_launch(void* const* d_in, const int* in_sizes, int n_in,
                              void* d_out, int out_size, void* d_ws, size_t ws_size,
                              hipStream_t stream)
{
    const float* query = (const float*)d_in[0];
    const float* key   = (const float*)d_in[1];
    const float* value = (const float*)d_in[2];
    const float* abias = (const float*)d_in[3];
    const int*   mask  = (const int*)d_in[4];
    const float* Wq = (const float*)d_in[5];
    const float* bq = (const float*)d_in[6];
    const float* Wk = (const float*)d_in[7];
    const float* bk = (const float*)d_in[8];
    const float* Wv = (const float*)d_in[9];
    const float* bv = (const float*)d_in[10];
    const float* Wo = (const float*)d_in[11];
    const float* bo = (const float*)d_in[12];
    float* out = (float*)d_out;

    // workspace layout (bf16 elements)
    const size_t T = (size_t)B_ * S_ * D_;   // 4 Mi
    const size_t WSZ = (size_t)D_ * D_;      // 1 Mi
    unsigned short* p = (unsigned short*)d_ws;
    unsigned short* qb  = p;  p += T;
    unsigned short* kb  = p;  p += T;
    unsigned short* vb  = p;  p += T;
    unsigned short* wqb = p;  p += WSZ;
    unsigned short* wkb = p;  p += WSZ;
    unsigned short* wvb = p;  p += WSZ;
    unsigned short* wob = p;  p += WSZ;
    unsigned short* Qpj = p;  p += T;
    unsigned short* Kpj = p;  p += T;
    unsigned short* VpT = p;  p += T;
    unsigned short* Xpj = p;  p += T;

    // converts
    cvt_bf16<<<dim3((int)(T / 4 / 256)), 256, 0, stream>>>(query, qb, (int)(T / 4));
    cvt_bf16<<<dim3((int)(T / 4 / 256)), 256, 0, stream>>>(key,   kb, (int)(T / 4));
    cvt_bf16<<<dim3((int)(T / 4 / 256)), 256, 0, stream>>>(value, vb, (int)(T / 4));
    cvt_bf16<<<dim3((int)(WSZ / 4 / 256)), 256, 0, stream>>>(Wq, wqb, (int)(WSZ / 4));
    cvt_bf16<<<dim3((int)(WSZ / 4 / 256)), 256, 0, stream>>>(Wk, wkb, (int)(WSZ / 4));
    cvt_bf16<<<dim3((int)(WSZ / 4 / 256)), 256, 0, stream>>>(Wv, wvb, (int)(WSZ / 4));
    cvt_bf16<<<dim3((int)(WSZ / 4 / 256)), 256, 0, stream>>>(Wo, wob, (int)(WSZ / 4));

    // projections (M=4096, N=1024, K=1024), grid (N/64, M/128) = (16, 32)
    dim3 gg(16, 32);
    gemm_mfma<<<gg, 256, 0, stream>>>(qb, wqb, bq, Qpj, 0);
    gemm_mfma<<<gg, 256, 0, stream>>>(kb, wkb, bk, Kpj, 0);
    gemm_mfma<<<gg, 256, 0, stream>>>(vb, wvb, bv, VpT, 1);

    // attention: grid B*H*(S/64) = 1024, XCD-swizzled
    attn_mfma<<<dim3(1024), 256, 0, stream>>>(Qpj, Kpj, VpT, abias, mask, Xpj);

    // output projection, f32 out
    gemm_mfma<<<gg, 256, 0, stream>>>(Xpj, wob, bo, out, 2);
}

// Round 3
// 582.940 us; speedup vs baseline: 3.6516x; 1.0935x over previous
//
#include <hip/hip_runtime.h>
#include <hip/hip_bf16.h>
#include <math.h>

#define B_ 4
#define S_ 1024
#define D_ 1024
#define H_ 16
#define DK_ 64

typedef short bf16x8 __attribute__((ext_vector_type(8)));
typedef float f32x4 __attribute__((ext_vector_type(4)));

#define MFMA(a, b, c) __builtin_amdgcn_mfma_f32_16x16x32_bf16(a, b, c, 0, 0, 0)

// async global->LDS, 16B per lane. Effective LDS dest = wave-uniform base + lane*16.
#define GLDS(gp, lp)                                                        \
    __builtin_amdgcn_global_load_lds(                                       \
        (const __attribute__((address_space(1))) void*)(const void*)(gp),   \
        (__attribute__((address_space(3))) void*)(void*)(lp), 16, 0, 0)

static __device__ __forceinline__ unsigned short f2bf(float f) {
    __hip_bfloat16 h = __float2bfloat16(f);
    return *reinterpret_cast<unsigned short*>(&h);
}
static __device__ __forceinline__ float bf2f(unsigned short u) {
    unsigned int x = ((unsigned int)u) << 16;
    union { unsigned int i; float f; } c; c.i = x; return c.f;
}

// ---------------------------------------------------------------------------
// fused f32->bf16 converts: 3 activations (4Mi elems each)
// ---------------------------------------------------------------------------
__global__ __launch_bounds__(256) void cvt3(
    const float* __restrict__ a, const float* __restrict__ b, const float* __restrict__ c,
    unsigned short* __restrict__ oa, unsigned short* __restrict__ ob, unsigned short* __restrict__ oc)
{
    int bx = blockIdx.x;
    int which = bx >> 12;                 // 4096 blocks per tensor
    const float* in = which == 0 ? a : which == 1 ? b : c;
    unsigned short* out = which == 0 ? oa : which == 1 ? ob : oc;
    int i = (bx & 4095) * 256 + threadIdx.x;   // float4 index, 1Mi per tensor
    float4 v = ((const float4*)in)[i];
    ushort4 o;
    o.x = f2bf(v.x); o.y = f2bf(v.y); o.z = f2bf(v.z); o.w = f2bf(v.w);
    ((ushort4*)out)[i] = o;
}

// 4 weight matrices (1Mi elems each)
__global__ __launch_bounds__(256) void cvt4(
    const float* __restrict__ a, const float* __restrict__ b,
    const float* __restrict__ c, const float* __restrict__ d,
    unsigned short* __restrict__ oa, unsigned short* __restrict__ ob,
    unsigned short* __restrict__ oc, unsigned short* __restrict__ od)
{
    int bx = blockIdx.x;
    int which = bx >> 10;                 // 1024 blocks per tensor
    const float* in = which == 0 ? a : which == 1 ? b : which == 2 ? c : d;
    unsigned short* out = which == 0 ? oa : which == 1 ? ob : which == 2 ? oc : od;
    int i = (bx & 1023) * 256 + threadIdx.x;
    float4 v = ((const float4*)in)[i];
    ushort4 o;
    o.x = f2bf(v.x); o.y = f2bf(v.y); o.z = f2bf(v.z); o.w = f2bf(v.w);
    ((ushort4*)out)[i] = o;
}

// ---------------------------------------------------------------------------
// bias prep: [B,S,S,H] f32 -> bf16 C-fragment-ordered tiles, with mask + /8
// folded in. Layout: elem(((((b*16+h)*64+q16)*16+kt)*64 + lane)*16 + v) where
// lane=(quad<<4)|lane16, v=j*4+r holds bias(b, q16*16+quad*4+r, kt*64+j*16+lane16, h).
// Block = (b,q16,kt), thread t: h=t&15, u=t>>4 (=lane16). Reads 256B-contig/wave.
// ---------------------------------------------------------------------------
__global__ __launch_bounds__(256) void prep_bias(
    const float* __restrict__ bias, const int* __restrict__ mask,
    unsigned short* __restrict__ biasP)
{
    const int t = threadIdx.x;
    const int h = t & 15, u = t >> 4;
    const int x = blockIdx.x;
    const int kt = x & 15, q16 = (x >> 4) & 63, b = x >> 10;

    const unsigned short NEG = f2bf(-28672.f);

    int mk[4];
    #pragma unroll
    for (int j = 0; j < 4; ++j) mk[j] = mask[b * 1024 + kt * 64 + j * 16 + u];

    const float* bb = bias + (((size_t)(b * 1024 + q16 * 16) * 1024) + kt * 64) * 16 + h;
    unsigned short* ob = biasP + ((((size_t)(b * 16 + h) * 64 + q16) * 16 + kt) * 64) * 16;

    #pragma unroll
    for (int quad = 0; quad < 4; ++quad) {
        bf16x8 v0, v1;
        #pragma unroll
        for (int r = 0; r < 4; ++r) {
            int q = quad * 4 + r;
            int mq = mask[b * 1024 + q16 * 16 + q];  // wave-uniform -> s_load
            #pragma unroll
            for (int j = 0; j < 4; ++j) {
                float v = bb[((size_t)q * 1024 + j * 16 + u) * 16];
                unsigned short pv = (mq && mk[j]) ? f2bf(v * 0.125f) : NEG;
                if (j < 2) v0[j * 4 + r] = (short)pv;
                else       v1[(j - 2) * 4 + r] = (short)pv;
            }
        }
        unsigned short* dst = ob + (size_t)(quad * 16 + u) * 16;
        *(bf16x8*)(dst) = v0;
        *(bf16x8*)(dst + 8) = v1;
    }
}

// ---------------------------------------------------------------------------
// m97-shape bf16 MFMA GEMM: C[4096,1024] = X @ W^T + bvec. Tile 128x128,
// BK=32, 4 waves of 64x64 (16 MFMA per 8 ds_read_b128 + 4 global_load_lds).
// z-fused: blockIdx.z selects (X,W,b,Y); mode = z unless mode_ovr >= 0.
// mode 0: Q-proj  -> bf16, *0.125, zero masked rows
// mode 1: K-proj  -> bf16 row-major
// mode 2: V-proj  -> bf16 transposed [(b*1024+n)][s] (8-B packed stores)
// mode 3: O-proj  -> f32 row-major
// ---------------------------------------------------------------------------
__global__ __launch_bounds__(256, 2) void gemm128(
    const unsigned short* __restrict__ X0, const unsigned short* __restrict__ X1,
    const unsigned short* __restrict__ X2,
    const unsigned short* __restrict__ W0, const unsigned short* __restrict__ W1,
    const unsigned short* __restrict__ W2,
    const float* __restrict__ bv0, const float* __restrict__ bv1,
    const float* __restrict__ bv2,
    void* __restrict__ Y0, void* __restrict__ Y1, void* __restrict__ Y2,
    const int* __restrict__ mask, int mode_ovr)
{
    __shared__ unsigned short As[128 * 32];
    __shared__ unsigned short Bs[128 * 32];

    const int z = blockIdx.z;
    const unsigned short* X = z == 0 ? X0 : z == 1 ? X1 : X2;
    const unsigned short* W = z == 0 ? W0 : z == 1 ? W1 : W2;
    const float* bvec = z == 0 ? bv0 : z == 1 ? bv1 : bv2;
    void* Yv = z == 0 ? Y0 : z == 1 ? Y1 : Y2;
    const int mode = mode_ovr >= 0 ? mode_ovr : z;

    const int t = threadIdx.x;
    const int w = t >> 6, l = t & 63;
    const int lane16 = l & 15, quad = l >> 4;
    const int m0 = blockIdx.y * 128, n0 = blockIdx.x * 128;
    const int wr = w >> 1, wc = w & 1;

    const int srow = w * 16 + (l >> 2);
    const unsigned short* agp = X + (size_t)(m0 + srow) * 1024 + (l & 3) * 8;
    const unsigned short* bgp = W + (size_t)(n0 + srow) * 1024 + (l & 3) * 8;
    unsigned short* alp = As + w * 512 + l * 8;
    unsigned short* blp = Bs + w * 512 + l * 8;

    f32x4 zero = {0.f, 0.f, 0.f, 0.f};
    f32x4 acc[4][4];
    #pragma unroll
    for (int i = 0; i < 4; ++i)
        #pragma unroll
        for (int j = 0; j < 4; ++j) acc[i][j] = zero;

    for (int kt = 0; kt < 1024; kt += 32) {
        GLDS(agp + kt, alp);
        GLDS(agp + kt + 64 * 1024, alp + 2048);
        GLDS(bgp + kt, blp);
        GLDS(bgp + kt + 64 * 1024, blp + 2048);
        __syncthreads();

        bf16x8 af[4], bfv[4];
        #pragma unroll
        for (int i = 0; i < 4; ++i)
            af[i] = *(const bf16x8*)(As + (wr * 64 + i * 16 + lane16) * 32 + quad * 8);
        #pragma unroll
        for (int j = 0; j < 4; ++j)
            bfv[j] = *(const bf16x8*)(Bs + (wc * 64 + j * 16 + lane16) * 32 + quad * 8);

        #pragma unroll
        for (int i = 0; i < 4; ++i)
            #pragma unroll
            for (int j = 0; j < 4; ++j)
                acc[i][j] = MFMA(af[i], bfv[j], acc[i][j]);
        __syncthreads();
    }

    float bvl[4];
    #pragma unroll
    for (int j = 0; j < 4; ++j) bvl[j] = bvec[n0 + wc * 64 + j * 16 + lane16];

    if (mode == 2) {
        // V transposed: out[(b*1024+n)][s], pack 4 consecutive s (r dim)
        const int bb = m0 >> 10;
        const int sb = (m0 & 1023) + wr * 64;
        #pragma unroll
        for (int i = 0; i < 4; ++i) {
            #pragma unroll
            for (int j = 0; j < 4; ++j) {
                int n = n0 + wc * 64 + j * 16 + lane16;
                ushort4 pk;
                pk.x = f2bf(acc[i][j][0] + bvl[j]);
                pk.y = f2bf(acc[i][j][1] + bvl[j]);
                pk.z = f2bf(acc[i][j][2] + bvl[j]);
                pk.w = f2bf(acc[i][j][3] + bvl[j]);
                int s = sb + i * 16 + quad * 4;
                *(ushort4*)((unsigned short*)Yv + ((size_t)(bb * 1024 + n)) * 1024 + s) = pk;
            }
        }
    } else if (mode == 3) {
        float* Y = (float*)Yv;
        #pragma unroll
        for (int i = 0; i < 4; ++i)
            #pragma unroll
            for (int j = 0; j < 4; ++j) {
                int n = n0 + wc * 64 + j * 16 + lane16;
                #pragma unroll
                for (int r = 0; r < 4; ++r) {
                    size_t m = m0 + wr * 64 + i * 16 + quad * 4 + r;
                    Y[m * 1024 + n] = acc[i][j][r] + bvl[j];
                }
            }
    } else {
        unsigned short* Y = (unsigned short*)Yv;
        #pragma unroll
        for (int i = 0; i < 4; ++i) {
            int mrow[4];
            #pragma unroll
            for (int r = 0; r < 4; ++r)
                mrow[r] = (mode == 0) ? mask[m0 + wr * 64 + i * 16 + quad * 4 + r] : 1;
            #pragma unroll
            for (int j = 0; j < 4; ++j) {
                int n = n0 + wc * 64 + j * 16 + lane16;
                #pragma unroll
                for (int r = 0; r < 4; ++r) {
                    size_t m = m0 + wr * 64 + i * 16 + quad * 4 + r;
                    float val = acc[i][j][r] + bvl[j];
                    if (mode == 0) val = mrow[r] ? val * 0.125f : 0.f;
                    Y[m * 1024 + n] = f2bf(val);
                }
            }
        }
    }
}

// ---------------------------------------------------------------------------
// MFMA flash attention. Block = (b,h,64 q), 4 waves x 16 q rows.
// Bias comes pre-masked/scaled/fragment-ordered from prep_bias: 2x16B loads/iter.
// Q pre-scaled by 0.125 (and masked rows zeroed) in projection.
// Block swizzle: bid = qt*64 + (b*16+h) -> all 16 q-tiles of a (b,h) share XCD.
// ---------------------------------------------------------------------------
__global__ __launch_bounds__(256, 2) void attn_mfma(
    const unsigned short* __restrict__ Qp, const unsigned short* __restrict__ Kp,
    const unsigned short* __restrict__ VpT, const unsigned short* __restrict__ biasP,
    unsigned short* __restrict__ Xp)
{
    __shared__ unsigned short Ks[64 * 64];
    __shared__ unsigned short Vs[64 * 64];
    __shared__ unsigned short Ps[4][16 * 72];

    const int t = threadIdx.x;
    const int w = t >> 6, l = t & 63;
    const int lane16 = l & 15, quad = l >> 4;

    const int bid = blockIdx.x;
    const int bh = bid & 63, qt = bid >> 6;
    const int h = bh & 15, b = bh >> 4;
    const int q0 = qt * 64;
    const int qrow0 = q0 + w * 16;
    const int q16 = qt * 4 + w;

    // Q fragments (bf16, pre-scaled): rows qrow0+lane16, k-chunks quad*8
    bf16x8 qf[2];
    #pragma unroll
    for (int c = 0; c < 2; ++c)
        qf[c] = *(const bf16x8*)(Qp + (size_t)(b * 1024 + qrow0 + lane16) * 1024
                                 + h * 64 + c * 32 + quad * 8);

    // bias fragment base for this wave/lane
    const unsigned short* bp = biasP
        + ((((size_t)(b * 16 + h) * 64 + q16) * 16) * 64 + l) * 16;

    // K/V staging (xor-swizzled 16B granules within 128B rows)
    const int krow = w * 8 + (l >> 3);
    const int kgran = (l & 7) ^ ((l >> 3) & 7);
    const unsigned short* kg = Kp + (size_t)(b * 1024 + krow) * 1024 + h * 64 + kgran * 8;
    unsigned short* klp = Ks + w * 512 + l * 8;
    const unsigned short* vg = VpT + ((size_t)(b * 16 + h) * 64 + krow) * 1024 + kgran * 8;
    unsigned short* vlp = Vs + w * 512 + l * 8;

    f32x4 zero = {0.f, 0.f, 0.f, 0.f};
    f32x4 o[4];
    #pragma unroll
    for (int j = 0; j < 4; ++j) o[j] = zero;
    float m_i[4] = {-1e30f, -1e30f, -1e30f, -1e30f};
    float l_i[4] = {0.f, 0.f, 0.f, 0.f};

    for (int kt16 = 0; kt16 < 16; ++kt16) {
        const int k0 = kt16 * 64;
        GLDS(kg + (size_t)k0 * 1024, klp);
        GLDS(kg + (size_t)(k0 + 32) * 1024, klp + 32 * 64);
        GLDS(vg + k0, vlp);
        GLDS(vg + k0 + 32 * 1024, vlp + 32 * 64);

        // bias fragment (independent of LDS) — issue before barrier
        bf16x8 bfr0 = *(const bf16x8*)(bp + (size_t)kt16 * 1024);
        bf16x8 bfr1 = *(const bf16x8*)(bp + (size_t)kt16 * 1024 + 8);
        __syncthreads();

        // S = Q K^T
        f32x4 s[4];
        #pragma unroll
        for (int j = 0; j < 4; ++j) {
            s[j] = zero;
            #pragma unroll
            for (int c = 0; c < 2; ++c) {
                bf16x8 kf = *(const bf16x8*)(Ks + (j * 16 + lane16) * 64
                                             + (((c * 4 + quad) ^ (lane16 & 7)) * 8));
                s[j] = MFMA(qf[c], kf, s[j]);
            }
        }

        // add prepped bias (mask & scale already folded)
        float sc[4][4];
        #pragma unroll
        for (int e = 0; e < 8; ++e) {
            sc[e >> 2][e & 3]       = s[e >> 2][e & 3]       + bf2f((unsigned short)bfr0[e]);
            sc[2 + (e >> 2)][e & 3] = s[2 + (e >> 2)][e & 3] + bf2f((unsigned short)bfr1[e]);
        }

        // online softmax (rows spread over 16 lanes of each quad-row group)
        float p[4][4];
        #pragma unroll
        for (int r = 0; r < 4; ++r) {
            float mx = fmaxf(fmaxf(sc[0][r], sc[1][r]), fmaxf(sc[2][r], sc[3][r]));
            #pragma unroll
            for (int d = 1; d < 16; d <<= 1) mx = fmaxf(mx, __shfl_xor(mx, d, 64));
            float mnew = fmaxf(m_i[r], mx);
            float alpha = __expf(m_i[r] - mnew);
            m_i[r] = mnew;
            float sum = 0.f;
            #pragma unroll
            for (int j = 0; j < 4; ++j) {
                p[j][r] = __expf(sc[j][r] - mnew);
                sum += p[j][r];
            }
            #pragma unroll
            for (int d = 1; d < 16; d <<= 1) sum += __shfl_xor(sum, d, 64);
            l_i[r] = l_i[r] * alpha + sum;
            #pragma unroll
            for (int jd = 0; jd < 4; ++jd) o[jd][r] *= alpha;
        }

        // P: C-layout -> LDS -> A-layout (intra-wave)
        #pragma unroll
        for (int j = 0; j < 4; ++j)
            #pragma unroll
            for (int r = 0; r < 4; ++r)
                Ps[w][(quad * 4 + r) * 72 + j * 16 + lane16] = f2bf(p[j][r]);
        asm volatile("" ::: "memory");

        bf16x8 pf[2];
        #pragma unroll
        for (int c = 0; c < 2; ++c)
            pf[c] = *(const bf16x8*)(&Ps[w][lane16 * 72 + c * 32 + quad * 8]);

        // O += P V
        #pragma unroll
        for (int jd = 0; jd < 4; ++jd)
            #pragma unroll
            for (int c = 0; c < 2; ++c) {
                bf16x8 vf = *(const bf16x8*)(Vs + (jd * 16 + lane16) * 64
                                             + (((c * 4 + quad) ^ (lane16 & 7)) * 8));
                o[jd] = MFMA(pf[c], vf, o[jd]);
            }
        __syncthreads();
    }

    float inv[4];
    #pragma unroll
    for (int r = 0; r < 4; ++r) inv[r] = 1.0f / l_i[r];

    #pragma unroll
    for (int jd = 0; jd < 4; ++jd)
        #pragma unroll
        for (int r = 0; r < 4; ++r)
            Xp[(size_t)(b * 1024 + qrow0 + quad * 4 + r) * 1024
               + h * 64 + jd * 16 + lane16] = f2bf(o[jd][r] * inv[r]);
}

// ---------------------------------------------------------------------------
extern "C" void kernel_launch(void* const* d_in, const int* in_sizes, int n_in,
                              void* d_out, int out_size, void* d_ws, size_t ws_size,
                              hipStream_t stream)
{
    const float* query = (const float*)d_in[0];
    const float* key   = (const float*)d_in[1];
    const float* value = (const float*)d_in[2];
    const float* abias = (const float*)d_in[3];
    const int*   mask  = (const int*)d_in[4];
    const float* Wq = (const float*)d_in[5];
    const float* bq = (const float*)d_in[6];
    const float* Wk = (const float*)d_in[7];
    const float* bk = (const float*)d_in[8];
    const float* Wv = (const float*)d_in[9];
    const float* bv = (const float*)d_in[10];
    const float* Wo = (const float*)d_in[11];
    const float* bo = (const float*)d_in[12];
    float* out = (float*)d_out;

    const size_t T = (size_t)B_ * S_ * D_;           // 4 Mi
    const size_t WSZ = (size_t)D_ * D_;              // 1 Mi
    const size_t BPSZ = (size_t)B_ * H_ * S_ * S_;   // 64 Mi
    unsigned short* p = (unsigned short*)d_ws;
    unsigned short* biasP = p;  p += BPSZ;
    unsigned short* qb  = p;  p += T;
    unsigned short* kb  = p;  p += T;
    unsigned short* vb  = p;  p += T;
    unsigned short* wqb = p;  p += WSZ;
    unsigned short* wkb = p;  p += WSZ;
    unsigned short* wvb = p;  p += WSZ;
    unsigned short* wob = p;  p += WSZ;
    unsigned short* Qpj = p;  p += T;
    unsigned short* Kpj = p;  p += T;
    unsigned short* VpT = p;  p += T;
    unsigned short* Xpj = p;  p += T;

    cvt3<<<dim3(3 * 4096), 256, 0, stream>>>(query, key, value, qb, kb, vb);
    cvt4<<<dim3(4 * 1024), 256, 0, stream>>>(Wq, Wk, Wv, Wo, wqb, wkb, wvb, wob);
    prep_bias<<<dim3(4096), 256, 0, stream>>>(abias, mask, biasP);

    // fused Q/K/V projections: grid (N/128, M/128, 3)
    gemm128<<<dim3(8, 32, 3), 256, 0, stream>>>(
        qb, kb, vb, wqb, wkb, wvb, bq, bk, bv,
        (void*)Qpj, (void*)Kpj, (void*)VpT, mask, -1);

    attn_mfma<<<dim3(1024), 256, 0, stream>>>(Qpj, Kpj, VpT, biasP, Xpj);

    // output projection (f32 out)
    gemm128<<<dim3(8, 32, 1), 256, 0, stream>>>(
        Xpj, Xpj, Xpj, wob, wob, wob, bo, bo, bo,
        (void*)out, (void*)out, (void*)out, mask, 3);
}